// Round 2
// 489.639 us; speedup vs baseline: 1.0206x; 1.0206x over previous
//
#include <hip/hip_runtime.h>
#include <hip/hip_bf16.h>
#include <math.h>

// ---------------- problem constants ----------------
#define BATCH 4
#define TLEN  2048
#define DIM   1024
#define NROWS (BATCH*TLEN)      // 8192
#define HDIM  (4*DIM)           // 4096

typedef __hip_bfloat16 bf16;
typedef __attribute__((ext_vector_type(8))) short   shortx8;   // 8 bf16 = 4 VGPR
typedef __attribute__((ext_vector_type(4))) float   floatx4;

__device__ __forceinline__ unsigned short f2bf(float f) {
    bf16 h = __float2bfloat16(f);
    return __builtin_bit_cast(unsigned short, h);
}

__device__ __forceinline__ void async16(const void* g, void* l) {
    // global -> LDS direct DMA, 16B/lane. LDS dest is wave-uniform base + lane*16.
    __builtin_amdgcn_global_load_lds((const __attribute__((address_space(1))) void*)g,
                                     (__attribute__((address_space(3))) void*)l, 16, 0, 0);
}

enum { EP_NONE=0, EP_SIGMOID=1, EP_ADD=2, EP_SQRELU=3, EP_FINAL=4 };

// ============================================================================
// Deep-pipelined GEMM: 128x256 tile, 512 threads (8 waves as 2x4),
// per-wave 64x64 output. K processed in 32-wide slices through a ring of
// FIVE 24KB LDS regions (region = A 128x32 + B 256x32 bf16; 120 KB total).
//
//  - phase q: issue 3 global_load_lds for slice q+4 (into the region retired
//    at the end of phase q-1), ds_read 8 fragments of slice q, 16 MFMA.
//  - end of phase: s_waitcnt vmcnt(9) (counted: 4 slices = 12 loads stay in
//    flight across barriers -- NEVER drained to 0 in the main loop) followed
//    by a raw s_barrier (no implicit vmcnt(0)/lgkmcnt(0) drain).
//  - setprio(1) around the MFMA cluster (T5).
//  - LDS swizzle: 16B slot of element (row,kg) = row*4 + (kg ^ ((row>>1)&3)),
//    realized by pre-swizzling the per-lane GLOBAL source address so the LDS
//    destination of global_load_lds stays linear; ds_read applies same XOR.
//  - XCD-bijective block swizzle on the flat workgroup id (nwg % 8 == 0 for
//    every launch here: 256 / 768 / 1024 blocks).
// Race freedom: a region is staged only after the barrier ending its reader
// phase; each wave waits on its own vmcnt before each barrier, so after the
// barrier every wave's contribution to the next region has landed.
// Barrier count is workgroup-uniform (1 + (P-4) + 3): no divergent s_barrier.
// ============================================================================
#define G_REGB   24576       // region bytes (A 8KB + B 16KB)
#define G_ABYTES 8192        // A sub-region bytes
#define G_NSH    (5*12288)   // 5 regions of 12288 shorts = 120 KB

__device__ __forceinline__ void gemm_core(
    const bf16* __restrict__ A, const bf16* __restrict__ Bt, const int K,
    const size_t m0, const size_t n0, short* lds, floatx4 (&acc)[4][4])
{
    const int tid = threadIdx.x;
    char* ldsc = (char*)lds;

    // ---- staging: pre-swizzled per-thread global sources, linear LDS dest.
    // A slot s = tid (512 slots): row = s>>2, kgroup = (s&3) ^ ((row>>1)&3)
    const int rA = tid >> 2;
    const int kA = ((tid & 3) ^ ((rA >> 1) & 3)) << 3;
    const bf16* pA  = A  + (size_t)(m0 + rA) * K + kA;
    // B slots j*512+tid (1024 slots over 256 rows)
    const int s1  = 512 + tid;
    const int rB1 = s1 >> 2;
    const int kB1 = ((s1 & 3) ^ ((rB1 >> 1) & 3)) << 3;
    const bf16* pB0 = Bt + (size_t)(n0 + rA)  * K + kA;   // slot tid: same math as A
    const bf16* pB1 = Bt + (size_t)(n0 + rB1) * K + kB1;
    char* dA  = ldsc + tid * 16;
    char* dB0 = ldsc + G_ABYTES + tid * 16;
    char* dB1 = ldsc + G_ABYTES + 8192 + tid * 16;

    // ---- MFMA fragment LDS byte offsets (swizzle-matched)
    const int lane = tid & 63;
    const int wave = tid >> 6;
    const int wm = (wave >> 2) * 64;     // 0 / 64
    const int wn = (wave & 3) * 64;      // 0 / 64 / 128 / 192
    const int lr = lane & 15, kq = lane >> 4;
    int offA[4], offB[4];
    #pragma unroll
    for (int i = 0; i < 4; ++i) {
        const int ra = wm + i*16 + lr;
        offA[i] = ra*64 + ((kq ^ ((ra>>1)&3)) << 4);
        const int rb = wn + i*16 + lr;
        offB[i] = G_ABYTES + rb*64 + ((kq ^ ((rb>>1)&3)) << 4);
    }

    const int P = K >> 5;        // 32-wide k-slices (32 or 128 here, always >= 5)

    auto stage = [&](int sl, int reg) {
        const int rB = reg * G_REGB;
        const int ko = sl << 5;
        async16(pA  + ko, dA  + rB);
        async16(pB0 + ko, dB0 + rB);
        async16(pB1 + ko, dB1 + rB);
    };
    auto compute = [&](int reg) {
        const char* rb = ldsc + reg * G_REGB;
        shortx8 af[4], bfr[4];
        #pragma unroll
        for (int i = 0; i < 4; ++i) af[i]  = *(const shortx8*)(rb + offA[i]);
        #pragma unroll
        for (int i = 0; i < 4; ++i) bfr[i] = *(const shortx8*)(rb + offB[i]);
        __builtin_amdgcn_s_setprio(1);
        #pragma unroll
        for (int mi = 0; mi < 4; ++mi)
            #pragma unroll
            for (int ni = 0; ni < 4; ++ni)
                acc[mi][ni] = __builtin_amdgcn_mfma_f32_16x16x32_bf16(
                                  af[mi], bfr[ni], acc[mi][ni], 0, 0, 0);
        __builtin_amdgcn_s_setprio(0);
    };

    // prologue: fill 4 regions, wait for slice 0 only (oldest 3 loads)
    stage(0,0); stage(1,1); stage(2,2); stage(3,3);
    asm volatile("s_waitcnt vmcnt(9)" ::: "memory");
    __builtin_amdgcn_s_barrier();
    __builtin_amdgcn_sched_barrier(0);

    int cur = 0, sreg = 4;
    for (int q = 0; q < P - 4; ++q) {
        stage(q + 4, sreg);          // into region retired at end of phase q-1
        compute(cur);                // slice q
        asm volatile("s_waitcnt vmcnt(9)" ::: "memory");   // slice q+1 landed
        __builtin_amdgcn_s_barrier();
        __builtin_amdgcn_sched_barrier(0);
        sreg = cur;
        cur  = (cur == 4) ? 0 : cur + 1;
    }
    // tail: 4 remaining slices, vmcnt steps down 6 -> 3 -> 0
    compute(cur); cur = (cur == 4) ? 0 : cur + 1;
    asm volatile("s_waitcnt vmcnt(6)" ::: "memory");
    __builtin_amdgcn_s_barrier();
    __builtin_amdgcn_sched_barrier(0);
    compute(cur); cur = (cur == 4) ? 0 : cur + 1;
    asm volatile("s_waitcnt vmcnt(3)" ::: "memory");
    __builtin_amdgcn_s_barrier();
    __builtin_amdgcn_sched_barrier(0);
    compute(cur); cur = (cur == 4) ? 0 : cur + 1;
    asm volatile("s_waitcnt vmcnt(0)" ::: "memory");
    __builtin_amdgcn_s_barrier();
    __builtin_amdgcn_sched_barrier(0);
    compute(cur);
}

// epilogue: C/D layout col=lane&15, row=(lane>>4)*4+reg (verified layout)
template<int MODE, typename OutT>
__device__ __forceinline__ void epilogue(
    floatx4 (&acc)[4][4], OutT* __restrict__ C,
    const float* __restrict__ addv, const bf16* __restrict__ mulv,
    const size_t m0, const size_t n0, const int N)
{
    const int tid = threadIdx.x;
    const int lane = tid & 63, wave = tid >> 6;
    const size_t r0 = m0 + (size_t)(wave >> 2) * 64 + ((lane >> 4) << 2);
    const size_t c0 = n0 + (size_t)(wave & 3) * 64 + (lane & 15);
    #pragma unroll
    for (int mi = 0; mi < 4; ++mi)
      #pragma unroll
      for (int ni = 0; ni < 4; ++ni)
        #pragma unroll
        for (int r = 0; r < 4; ++r) {
            const size_t off = (r0 + mi*16 + r) * N + c0 + ni*16;
            float v = acc[mi][ni][r];
            if (MODE == EP_SIGMOID)      v = 1.0f / (1.0f + __expf(-v));
            else if (MODE == EP_ADD)     v = addv[off] + v;
            else if (MODE == EP_SQRELU)  { float t = fmaxf(v, 0.0f); v = t * t; }
            else if (MODE == EP_FINAL)   v = addv[off] + __bfloat162float(mulv[off]) * v;
            if (sizeof(OutT) == 2) *(unsigned short*)(C + off) = f2bf(v);
            else                   *(float*)(C + off) = v;
        }
}

template<int MODE, typename OutT>
__global__ __launch_bounds__(512, 2)
void gemm256(const bf16* __restrict__ A, const bf16* __restrict__ Bt,
             OutT* __restrict__ C,
             const float* __restrict__ addv, const bf16* __restrict__ mulv,
             int N, int K)
{
    __shared__ __align__(16) short lds[G_NSH];
    const int nwg  = gridDim.x * gridDim.y;
    const int orig = blockIdx.y * gridDim.x + blockIdx.x;
    const int wg   = (orig & 7) * (nwg >> 3) + (orig >> 3);   // nwg % 8 == 0
    const int bx   = wg % gridDim.x;
    const int by   = wg / gridDim.x;
    const size_t m0 = (size_t)bx * 128;
    const size_t n0 = (size_t)by * 256;
    floatx4 acc[4][4] = {};
    gemm_core(A, Bt, K, m0, n0, lds, acc);
    epilogue<MODE, OutT>(acc, C, addv, mulv, m0, n0, N);
}

// ---------------------------------------------------------------------------
// Multi-GEMM: k/v/r (same M=8192, K=1024, N=1024, bf16 out) in ONE dispatch.
// grid = (64, 12): 4 col tiles per descriptor.
// ---------------------------------------------------------------------------
struct GDesc { const bf16* A; const bf16* Bt; bf16* C; int mode; };
struct GArgs { GDesc d[3]; };

__global__ __launch_bounds__(512, 2)
void gemm256_multi(GArgs args)
{
    __shared__ __align__(16) short lds[G_NSH];
    const int nwg  = gridDim.x * gridDim.y;
    const int orig = blockIdx.y * gridDim.x + blockIdx.x;
    const int wg   = (orig & 7) * (nwg >> 3) + (orig >> 3);
    const int bx   = wg % gridDim.x;
    const int byg  = wg / gridDim.x;         // 0..11
    const int di   = byg >> 2;
    const int by   = byg & 3;
    const GDesc d  = args.d[di];
    const size_t m0 = (size_t)bx * 128;
    const size_t n0 = (size_t)by * 256;
    floatx4 acc[4][4] = {};
    gemm_core(d.A, d.Bt, DIM, m0, n0, lds, acc);

    const int tid = threadIdx.x;
    const int lane = tid & 63, wave = tid >> 6;
    const size_t r0 = m0 + (size_t)(wave >> 2) * 64 + ((lane >> 4) << 2);
    const size_t c0 = n0 + (size_t)(wave & 3) * 64 + (lane & 15);
    const bool sig = (d.mode == EP_SIGMOID);
    #pragma unroll
    for (int mi = 0; mi < 4; ++mi)
      #pragma unroll
      for (int ni = 0; ni < 4; ++ni)
        #pragma unroll
        for (int r = 0; r < 4; ++r) {
            const size_t off = (r0 + mi*16 + r) * DIM + c0 + ni*16;
            float v = acc[mi][ni][r];
            if (sig) v = 1.0f / (1.0f + __expf(-v));
            *(unsigned short*)(d.C + off) = f2bf(v);
        }
}

// ---------------------------------------------------------------------------
// Prep: all 7 weight transposes (fp32 KxN -> bf16 NxK) + 3-output time-mix,
// one dispatch. Block (32,8) = 256 threads.
// ---------------------------------------------------------------------------
struct TDesc { const float* in; bf16* out; int K; int N; int tiles; int tx; };
struct PrepArgs {
    TDesc t[7];
    int ttotal;
    const float4 *x, *mk, *mv, *mr;
    ushort4 *ok, *ov, *orr;
};

__global__ __launch_bounds__(256)
void prep_kernel(PrepArgs a)
{
    int blk = blockIdx.x;
    if (blk < a.ttotal) {
        int t = blk, di = 0;
        while (t >= a.t[di].tiles) { t -= a.t[di].tiles; ++di; }
        const float* in  = a.t[di].in;
        bf16*        out = a.t[di].out;
        const int K = a.t[di].K, N = a.t[di].N, tx = a.t[di].tx;
        const int bx = t % tx, by = t / tx;
        __shared__ float tile[32][33];
        const int kt = by * 32, nt = bx * 32;
        #pragma unroll
        for (int i = threadIdx.y; i < 32; i += 8)
            tile[i][threadIdx.x] = in[(size_t)(kt + i) * N + nt + threadIdx.x];
        __syncthreads();
        #pragma unroll
        for (int i = threadIdx.y; i < 32; i += 8)
            out[(size_t)(nt + i) * K + kt + threadIdx.x] =
                __float2bfloat16(tile[threadIdx.x][i]);
    } else {
        const int D4 = DIM / 4;
        int tid = threadIdx.y * 32 + threadIdx.x;
        int e   = (blk - a.ttotal) * 256 + tid;
        int d4  = e & (D4 - 1);
        int t   = (e >> 8) & (TLEN - 1);
        float4 xc = a.x[e];
        float4 sh = make_float4(0.f, 0.f, 0.f, 0.f);
        if (t > 0) sh = a.x[e - D4];
        float4 mk = a.mk[d4], mv = a.mv[d4], mr = a.mr[d4];
        ushort4 u;
        u.x=f2bf(xc.x*mk.x+sh.x*(1.f-mk.x)); u.y=f2bf(xc.y*mk.y+sh.y*(1.f-mk.y));
        u.z=f2bf(xc.z*mk.z+sh.z*(1.f-mk.z)); u.w=f2bf(xc.w*mk.w+sh.w*(1.f-mk.w));
        a.ok[e]=u;
        u.x=f2bf(xc.x*mv.x+sh.x*(1.f-mv.x)); u.y=f2bf(xc.y*mv.y+sh.y*(1.f-mv.y));
        u.z=f2bf(xc.z*mv.z+sh.z*(1.f-mv.z)); u.w=f2bf(xc.w*mv.w+sh.w*(1.f-mv.w));
        a.ov[e]=u;
        u.x=f2bf(xc.x*mr.x+sh.x*(1.f-mr.x)); u.y=f2bf(xc.y*mr.y+sh.y*(1.f-mr.y));
        u.z=f2bf(xc.z*mr.z+sh.z*(1.f-mr.z)); u.w=f2bf(xc.w*mr.w+sh.w*(1.f-mr.w));
        a.orr[e]=u;
    }
}

// fused 2-output token-shift mix (channel mixing)
__global__ __launch_bounds__(256)
void mix2_kernel(const float4* __restrict__ x,
                 const float4* __restrict__ mk, const float4* __restrict__ mr,
                 ushort4* __restrict__ ok, ushort4* __restrict__ orr)
{
    const int D4 = DIM / 4;
    int e   = blockIdx.x * 256 + threadIdx.x;
    int d4  = e & (D4 - 1);
    int t   = (e >> 8) & (TLEN - 1);
    float4 xc = x[e];
    float4 sh = make_float4(0.f, 0.f, 0.f, 0.f);
    if (t > 0) sh = x[e - D4];
    float4 a = mk[d4], c = mr[d4];
    ushort4 u;
    u.x=f2bf(xc.x*a.x+sh.x*(1.f-a.x)); u.y=f2bf(xc.y*a.y+sh.y*(1.f-a.y));
    u.z=f2bf(xc.z*a.z+sh.z*(1.f-a.z)); u.w=f2bf(xc.w*a.w+sh.w*(1.f-a.w));
    ok[e]=u;
    u.x=f2bf(xc.x*c.x+sh.x*(1.f-c.x)); u.y=f2bf(xc.y*c.y+sh.y*(1.f-c.y));
    u.z=f2bf(xc.z*c.z+sh.z*(1.f-c.z)); u.w=f2bf(xc.w*c.w+sh.w*(1.f-c.w));
    orr[e]=u;
}

// WKV scan, chunk-parallel + 64-step discarded warmup (ew <= ~0.5 per channel
// -> carry influence < 1e-19 after warmup). out = r*wkv, may alias R.
#define WKV_CHUNK 64
#define WKV_WARM  64
__global__ __launch_bounds__(256)
void wkv_kernel(const bf16* __restrict__ K, const bf16* __restrict__ V,
                const bf16* __restrict__ R, const float* __restrict__ td,
                bf16* __restrict__ out)
{
    int d     = blockIdx.x * 256 + threadIdx.x;
    int chunk = blockIdx.y;
    int b     = blockIdx.z;
    int start = chunk * WKV_CHUNK;
    int t0    = start - WKV_WARM; if (t0 < 0) t0 = 0;

    float ew = __expf(-__expf(td[d]));
    float num = 0.f, den = 0.f;
    size_t base = ((size_t)b * TLEN) * DIM + d;

    for (int t = t0; t < start; ++t) {
        size_t idx = base + (size_t)t * DIM;
        float ek = __expf(__bfloat162float(K[idx]));
        num = ew * num + ek * __bfloat162float(V[idx]);
        den = ew * den + ek;
    }
    for (int t = start; t < start + WKV_CHUNK; ++t) {
        size_t idx = base + (size_t)t * DIM;
        float ek = __expf(__bfloat162float(K[idx]));
        num = ew * num + ek * __bfloat162float(V[idx]);
        den = ew * den + ek;
        out[idx] = __float2bfloat16(__bfloat162float(R[idx]) * (num / (den + 1e-6f)));
    }
}

extern "C" void kernel_launch(void* const* d_in, const int* in_sizes, int n_in,
                              void* d_out, int out_size, void* d_ws, size_t ws_size,
                              hipStream_t stream)
{
    const float* x   = (const float*)d_in[0];
    const float* td  = (const float*)d_in[1];
    const float* tmk = (const float*)d_in[2];
    const float* tmv = (const float*)d_in[3];
    const float* tmr = (const float*)d_in[4];
    const float* Wk  = (const float*)d_in[5];
    const float* Wv  = (const float*)d_in[6];
    const float* Wr  = (const float*)d_in[7];
    const float* Wo  = (const float*)d_in[8];
    const float* cmk = (const float*)d_in[9];
    const float* cmr = (const float*)d_in[10];
    const float* Wck = (const float*)d_in[11];
    const float* Wcv = (const float*)d_in[12];
    const float* Wcr = (const float*)d_in[13];
    float* out = (float*)d_out;

    // ---- workspace layout: 154 MB peak ----
    // Lifetimes (RACE-CHECKED):
    //  0-26   weights (whole run)
    //  26-58  f0 = x1 fp32 (step 5 -> end)
    //  58-74  bA: xk (2-3) -> xr2 (6-7) -> kh[0:16MB) (8-9)
    //  74-90  bB: xv (2-4) -> kh (8-9)
    //  90-106 bC: xr (2-3) -> kh (8-9)
    //  106-122 bD: k (3-4) -> kh (8-9)
    //  122-138 bE: v (3-4) -> xk2 (6-8)   [kh ends at 122: NO overlap w/ xk2]
    //  138-154 bF: r (3) -> rwkv (4-5) -> r2 (7-9)
    char* ws = (char*)d_ws;
    const size_t MB = 1024 * 1024;
    bf16*  Wk_t  = (bf16*)(ws +   0*MB);
    bf16*  Wv_t  = (bf16*)(ws +   2*MB);
    bf16*  Wr_t  = (bf16*)(ws +   4*MB);
    bf16*  Wo_t  = (bf16*)(ws +   6*MB);
    bf16*  Wcr_t = (bf16*)(ws +   8*MB);
    bf16*  Wck_t = (bf16*)(ws +  10*MB);  // 4096x1024 NxK, 8MB
    bf16*  Wcv_t = (bf16*)(ws +  18*MB);  // 1024x4096 NxK, 8MB
    float* f0    = (float*)(ws + 26*MB);
    bf16*  bA    = (bf16*)(ws +  58*MB);
    bf16*  bB    = (bf16*)(ws +  74*MB);
    bf16*  bC    = (bf16*)(ws +  90*MB);
    bf16*  bD    = (bf16*)(ws + 106*MB);
    bf16*  bE    = (bf16*)(ws + 122*MB);
    bf16*  bF    = (bf16*)(ws + 138*MB);
    bf16*  kh    = bA;                    // 8192x4096 bf16 = 64MB @ 58..122

    const dim3 blk(256);
    const dim3 gblk(512);

    // 1) prep: 7 transposes + time-mix (xk->bA, xv->bB, xr->bC), one dispatch
    {
        PrepArgs pa;
        const float* src[7] = {Wk, Wv, Wr, Wo, Wcr, Wck, Wcv};
        bf16*        dst[7] = {Wk_t, Wv_t, Wr_t, Wo_t, Wcr_t, Wck_t, Wcv_t};
        int          kk[7]  = {DIM, DIM, DIM, DIM, DIM, DIM, HDIM};
        int          nn[7]  = {DIM, DIM, DIM, DIM, DIM, HDIM, DIM};
        int total = 0;
        for (int i = 0; i < 7; ++i) {
            int tx = nn[i] / 32, ty = kk[i] / 32;
            pa.t[i] = {src[i], dst[i], kk[i], nn[i], tx * ty, tx};
            total += tx * ty;
        }
        pa.ttotal = total;
        pa.x  = (const float4*)x;
        pa.mk = (const float4*)tmk; pa.mv = (const float4*)tmv; pa.mr = (const float4*)tmr;
        pa.ok = (ushort4*)bA; pa.ov = (ushort4*)bB; pa.orr = (ushort4*)bC;
        const int mixBlocks = NROWS * DIM / 4 / 256;   // 8192
        prep_kernel<<<dim3(total + mixBlocks), dim3(32, 8), 0, stream>>>(pa);
    }

    // 2) k, v, r GEMMs fused: grid (64, 12) = 768 blocks (3 full CU waves)
    {
        GArgs ga;
        ga.d[0] = {bA, Wk_t, bD, EP_NONE};
        ga.d[1] = {bB, Wv_t, bE, EP_NONE};
        ga.d[2] = {bC, Wr_t, bF, EP_SIGMOID};
        gemm256_multi<<<dim3(NROWS/128, 12), gblk, 0, stream>>>(ga);
    }

    // 3) WKV scan (rwkv = r*wkv, in place over bF)
    dim3 wkvGrid(DIM / 256, TLEN / WKV_CHUNK, BATCH);
    wkv_kernel<<<wkvGrid, blk, 0, stream>>>(bD, bE, bF, td, bF);

    // 4) x1 = x + rwkv @ Wo -> f0 (fp32)   grid 64x4 = 256 blocks (1/CU)
    gemm256<EP_ADD, float><<<dim3(NROWS/128, DIM/256), gblk, 0, stream>>>(
        bF, Wo_t, f0, x, nullptr, DIM, DIM);

    // 5) channel-mix: xk2 -> bE, xr2 -> bA
    mix2_kernel<<<dim3(NROWS * DIM / 4 / 256), blk, 0, stream>>>(
        (const float4*)f0, (const float4*)cmk, (const float4*)cmr,
        (ushort4*)bE, (ushort4*)bA);

    // 6) r2 = sigmoid(xr2 @ Wcr) -> bF  (reads bA BEFORE kh overwrites it)
    gemm256<EP_SIGMOID, bf16><<<dim3(NROWS/128, DIM/256), gblk, 0, stream>>>(
        bA, Wcr_t, bF, nullptr, nullptr, DIM, DIM);

    // 7) kh = sqrelu(xk2 @ Wck) -> 58..122MB   grid 64x16 = 1024 blocks
    gemm256<EP_SQRELU, bf16><<<dim3(NROWS/128, HDIM/256), gblk, 0, stream>>>(
        bE, Wck_t, kh, nullptr, nullptr, HDIM, DIM);

    // 8) out = x1 + r2 * (kh @ Wcv)
    gemm256<EP_FINAL, float><<<dim3(NROWS/128, DIM/256), gblk, 0, stream>>>(
        kh, Wcv_t, out, f0, bF, DIM, HDIM);
}